// Round 1
// baseline (989.849 us; speedup 1.0000x reference)
//
#include <hip/hip_runtime.h>
#include <hip/hip_bf16.h>
#include <math.h>

// Problem constants
#define DD   2048
#define SS   2048
#define HH   16
#define HDIM 128
#define BB   2
#define MM   4096   // B*S rows
#define D4   8192

using bf16x8 = __attribute__((ext_vector_type(8))) short;
using f32x4  = __attribute__((ext_vector_type(4))) float;

__device__ __forceinline__ ushort f2bf(float x) {
  uint u = __builtin_bit_cast(uint, x);
  u += 0x7FFFu + ((u >> 16) & 1u);   // round-to-nearest-even
  return (ushort)(u >> 16);
}

__device__ __forceinline__ float gelu_f(float v) {
  // jax.nn.gelu default (approximate=True, tanh form)
  float u = 0.7978845608028654f * (v + 0.044715f * v * v * v);
  float e = __expf(2.0f * u);
  float th = 1.0f - 2.0f / (e + 1.0f);   // robust tanh (inf-safe)
  return 0.5f * v * (1.0f + th);
}

__device__ __forceinline__ void gload_lds16(const void* g, void* l) {
  __builtin_amdgcn_global_load_lds(
      (const __attribute__((address_space(1))) void*)g,
      (__attribute__((address_space(3))) void*)l, 16, 0, 0);
}

// ---------------------------------------------------------------- f32 -> bf16
__global__ __launch_bounds__(256) void cvt_f32_bf16(
    const float* __restrict__ in, ushort* __restrict__ out, int n4) {
  int i = blockIdx.x * 256 + threadIdx.x;
  if (i >= n4) return;
  float4 v = ((const float4*)in)[i];
  ushort4 o;
  o.x = f2bf(v.x); o.y = f2bf(v.y); o.z = f2bf(v.z); o.w = f2bf(v.w);
  ((ushort4*)out)[i] = o;
}

// ---------------------------------------------------------------- LayerNorm
// one block (256 thr) per row of 2048; writes f32 and bf16 copies
__global__ __launch_bounds__(256) void ln_rows(
    const float* __restrict__ in, const float* __restrict__ gam,
    const float* __restrict__ bet, float* __restrict__ outf,
    ushort* __restrict__ outb) {
  int row = blockIdx.x;
  int t = threadIdx.x;
  const float4* r4 = (const float4*)(in + (size_t)row * DD);
  float4 v0 = r4[t], v1 = r4[t + 256];
  float s = v0.x + v0.y + v0.z + v0.w + v1.x + v1.y + v1.z + v1.w;
  __shared__ float redA[4], redB[4];
  #pragma unroll
  for (int off = 32; off >= 1; off >>= 1) s += __shfl_xor(s, off);
  if ((t & 63) == 0) redA[t >> 6] = s;
  __syncthreads();
  float mean = (redA[0] + redA[1] + redA[2] + redA[3]) * (1.0f / DD);
  float d0 = v0.x - mean, d1 = v0.y - mean, d2 = v0.z - mean, d3 = v0.w - mean;
  float d4 = v1.x - mean, d5 = v1.y - mean, d6 = v1.z - mean, d7 = v1.w - mean;
  float q = d0*d0 + d1*d1 + d2*d2 + d3*d3 + d4*d4 + d5*d5 + d6*d6 + d7*d7;
  #pragma unroll
  for (int off = 32; off >= 1; off >>= 1) q += __shfl_xor(q, off);
  if ((t & 63) == 0) redB[t >> 6] = q;
  __syncthreads();
  float var = (redB[0] + redB[1] + redB[2] + redB[3]) * (1.0f / DD);
  float rstd = rsqrtf(var + 1e-5f);
  const float4* g4 = (const float4*)gam;
  const float4* b4 = (const float4*)bet;
  float4 g0 = g4[t], g1 = g4[t + 256], bb0 = b4[t], bb1 = b4[t + 256];
  float4 y0, y1;
  y0.x = d0 * rstd * g0.x + bb0.x;  y0.y = d1 * rstd * g0.y + bb0.y;
  y0.z = d2 * rstd * g0.z + bb0.z;  y0.w = d3 * rstd * g0.w + bb0.w;
  y1.x = d4 * rstd * g1.x + bb1.x;  y1.y = d5 * rstd * g1.y + bb1.y;
  y1.z = d6 * rstd * g1.z + bb1.z;  y1.w = d7 * rstd * g1.w + bb1.w;
  float4* of4 = (float4*)(outf + (size_t)row * DD);
  of4[t] = y0; of4[t + 256] = y1;
  ushort4 u0, u1;
  u0.x = f2bf(y0.x); u0.y = f2bf(y0.y); u0.z = f2bf(y0.z); u0.w = f2bf(y0.w);
  u1.x = f2bf(y1.x); u1.y = f2bf(y1.y); u1.z = f2bf(y1.z); u1.w = f2bf(y1.w);
  ushort4* ob4 = (ushort4*)(outb + (size_t)row * DD);
  ob4[t] = u0; ob4[t + 256] = u1;
}

// ---------------------------------------------------------------- GEMM
// C[M,N] = A[M,K](bf16) @ Bt[N,K](bf16)^T + bias[N] (+res) (gelu) -> f32|bf16
// 128x128 tile, BK=32, 4 waves (2x2 of 64x64). LDS src-swizzled for
// global_load_lds (chunk' = chunk ^ ((row>>1)&3)) -> 2-way-free frag reads.
template <bool OBF16, bool GELU_, bool RES_>
__global__ __launch_bounds__(256) void gemm_bt(
    const ushort* __restrict__ A, const ushort* __restrict__ Bt,
    const float* __restrict__ bias, const float* __restrict__ res,
    void* __restrict__ Cout, int M, int N, int K) {
  __shared__ ushort As[128 * 32];
  __shared__ ushort Bs[128 * 32];
  const int nbm = M >> 7;
  int bm = blockIdx.x % nbm, bn = blockIdx.x / nbm;
  int m0 = bm << 7, n0 = bn << 7;
  int t = threadIdx.x, lane = t & 63, w = t >> 6;
  int wr = (w >> 1) * 64, wc = (w & 1) * 64;
  int lr = lane & 15, lg = lane >> 4;

  f32x4 acc[4][4] = {};
  int srow = t >> 2;
  int schunk = t & 3;
  int sc = (schunk ^ ((srow >> 1) & 3)) * 8;   // swizzled k-offset (elements)

  for (int k0 = 0; k0 < K; k0 += 32) {
    const ushort* Ab = A + (size_t)(m0 + srow) * K + k0;
    const ushort* Bb = Bt + (size_t)(n0 + srow) * K + k0;
    gload_lds16(Ab + sc, &As[t * 8]);
    gload_lds16(Ab + (size_t)64 * K + sc, &As[2048 + t * 8]);
    gload_lds16(Bb + sc, &Bs[t * 8]);
    gload_lds16(Bb + (size_t)64 * K + sc, &Bs[2048 + t * 8]);
    __syncthreads();
    bf16x8 af[4], bf_[4];
    #pragma unroll
    for (int mi = 0; mi < 4; mi++) {
      int row = wr + mi * 16 + lr;
      af[mi] = *(const bf16x8*)&As[row * 32 + ((lg ^ ((row >> 1) & 3)) << 3)];
    }
    #pragma unroll
    for (int ni = 0; ni < 4; ni++) {
      int row = wc + ni * 16 + lr;
      bf_[ni] = *(const bf16x8*)&Bs[row * 32 + ((lg ^ ((row >> 1) & 3)) << 3)];
    }
    #pragma unroll
    for (int mi = 0; mi < 4; mi++)
      #pragma unroll
      for (int ni = 0; ni < 4; ni++)
        acc[mi][ni] = __builtin_amdgcn_mfma_f32_16x16x32_bf16(
            af[mi], bf_[ni], acc[mi][ni], 0, 0, 0);
    __syncthreads();
  }

  float bv[4];
  #pragma unroll
  for (int ni = 0; ni < 4; ni++) bv[ni] = bias[n0 + wc + ni * 16 + lr];
  #pragma unroll
  for (int mi = 0; mi < 4; mi++) {
    #pragma unroll
    for (int r = 0; r < 4; r++) {
      int m = m0 + wr + mi * 16 + lg * 4 + r;
      #pragma unroll
      for (int ni = 0; ni < 4; ni++) {
        int n = n0 + wc + ni * 16 + lr;
        size_t idx = (size_t)m * N + n;
        float v = acc[mi][ni][r] + bv[ni];
        if (RES_) v += res[idx];
        if (GELU_) v = gelu_f(v);
        if (OBF16) ((ushort*)Cout)[idx] = f2bf(v);
        else       ((float*)Cout)[idx] = v;
      }
    }
  }
}

// ---------------------------------------------------------------- Attention
// Causal flash attention. grid = B*H*(S/64); 4 waves x 16 q-rows.
// KVT=32. K staged via swizzled global_load_lds; V staged transposed in LDS;
// P round-trips through per-wave LDS to reach MFMA A-layout.
__global__ __launch_bounds__(256) void attn_fwd(
    const ushort* __restrict__ qb, const ushort* __restrict__ kb,
    const ushort* __restrict__ vb, ushort* __restrict__ ob) {
  __shared__ ushort Ks[32 * 128];     // [kv][128], chunk' = chunk ^ (kv&7)
  __shared__ ushort Vt[128 * 32];     // [d][kv],  chunk' = chunk ^ ((d>>1)&3)
  __shared__ ushort Ps[4][16 * 32];   // per wave, chunk' = chunk ^ ((q>>1)&3)

  int blk = blockIdx.x;
  int qt = 31 - (blk & 31);           // longest blocks first
  int bh = blk >> 5;
  int b = bh >> 4, h = bh & 15;
  int q0 = qt * 64;
  int t = threadIdx.x, lane = t & 63, w = t >> 6;
  int lr = lane & 15, lg = lane >> 4;
  const size_t base = (size_t)b * SS * DD + (size_t)h * HDIM;
  const ushort* qp = qb + base;
  const ushort* kp = kb + base;
  const ushort* vp = vb + base;
  int wq0 = q0 + w * 16;

  bf16x8 qf[4];
  #pragma unroll
  for (int kk = 0; kk < 4; kk++)
    qf[kk] = *(const bf16x8*)(qp + (size_t)(wq0 + lr) * DD + kk * 32 + lg * 8);

  f32x4 o[8] = {};
  float mrow[4] = {-1e30f, -1e30f, -1e30f, -1e30f};
  float lrow[4] = {0.f, 0.f, 0.f, 0.f};
  const float scale = 0.08838834764831845f;   // 1/sqrt(128)

  for (int kv0 = 0; kv0 < q0 + 64; kv0 += 32) {
    {   // stage K (swizzled source so LDS stays linear for global_load_lds)
      int s0 = t, row0 = s0 >> 4, cp0 = s0 & 15;
      gload_lds16(kp + (size_t)(kv0 + row0) * DD + ((cp0 ^ (row0 & 7)) << 3),
                  &Ks[s0 * 8]);
      int s1 = 256 + t, row1 = s1 >> 4, cp1 = s1 & 15;
      gload_lds16(kp + (size_t)(kv0 + row1) * DD + ((cp1 ^ (row1 & 7)) << 3),
                  &Ks[s1 * 8]);
    }
    {   // stage V transposed
      int kv = t >> 3;
      int d0 = (t & 7) * 16;
      const ushort* vrow = vp + (size_t)(kv0 + kv) * DD + d0;
      bf16x8 x0 = *(const bf16x8*)vrow;
      bf16x8 x1 = *(const bf16x8*)(vrow + 8);
      #pragma unroll
      for (int i = 0; i < 16; i++) {
        int d = d0 + i;
        ushort val = (ushort)((i < 8) ? x0[i] : x1[i - 8]);
        int swc = (kv >> 3) ^ ((d >> 1) & 3);
        Vt[d * 32 + swc * 8 + (kv & 7)] = val;
      }
    }
    __syncthreads();

    if (kv0 <= wq0 + 15) {   // tile not fully masked for this wave
      f32x4 sc[2] = {};
      #pragma unroll
      for (int nt = 0; nt < 2; nt++) {
        int kvr = nt * 16 + lr;
        #pragma unroll
        for (int kk = 0; kk < 4; kk++) {
          int c0 = kk * 4 + lg;
          bf16x8 kf = *(const bf16x8*)&Ks[kvr * 128 + ((c0 ^ (kvr & 7)) << 3)];
          sc[nt] = __builtin_amdgcn_mfma_f32_16x16x32_bf16(qf[kk], kf, sc[nt],
                                                           0, 0, 0);
        }
      }
      float p[2][4], fr[4];
      #pragma unroll
      for (int r = 0; r < 4; r++) {
        int qg = wq0 + lg * 4 + r;
        float v0 = sc[0][r] * scale; if (kv0 + lr > qg)      v0 = -1e30f;
        float v1 = sc[1][r] * scale; if (kv0 + 16 + lr > qg) v1 = -1e30f;
        p[0][r] = v0; p[1][r] = v1;
        float m_ = fmaxf(v0, v1);
        m_ = fmaxf(m_, __shfl_xor(m_, 1));
        m_ = fmaxf(m_, __shfl_xor(m_, 2));
        m_ = fmaxf(m_, __shfl_xor(m_, 4));
        m_ = fmaxf(m_, __shfl_xor(m_, 8));
        float mn = fmaxf(mrow[r], m_);
        fr[r] = __expf(mrow[r] - mn);
        mrow[r] = mn;
        float p0 = __expf(p[0][r] - mn), p1 = __expf(p[1][r] - mn);
        p[0][r] = p0; p[1][r] = p1;
        float s_ = p0 + p1;
        s_ += __shfl_xor(s_, 1); s_ += __shfl_xor(s_, 2);
        s_ += __shfl_xor(s_, 4); s_ += __shfl_xor(s_, 8);
        lrow[r] = lrow[r] * fr[r] + s_;
      }
      #pragma unroll
      for (int dt = 0; dt < 8; dt++)
        #pragma unroll
        for (int r = 0; r < 4; r++) o[dt][r] *= fr[r];
      #pragma unroll
      for (int nt = 0; nt < 2; nt++) {
        #pragma unroll
        for (int r = 0; r < 4; r++) {
          int prow = lg * 4 + r;
          int col = nt * 16 + lr;
          int swc = (col >> 3) ^ ((prow >> 1) & 3);
          Ps[w][prow * 32 + swc * 8 + (col & 7)] = f2bf(p[nt][r]);
        }
      }
      asm volatile("s_waitcnt lgkmcnt(0)" ::: "memory");
      bf16x8 pf = *(const bf16x8*)&Ps[w][lr * 32 + ((lg ^ ((lr >> 1) & 3)) << 3)];
      #pragma unroll
      for (int dt = 0; dt < 8; dt++) {
        int d = dt * 16 + lr;
        bf16x8 vf = *(const bf16x8*)&Vt[d * 32 + ((lg ^ ((d >> 1) & 3)) << 3)];
        o[dt] = __builtin_amdgcn_mfma_f32_16x16x32_bf16(pf, vf, o[dt], 0, 0, 0);
      }
    }
    __syncthreads();
  }

  #pragma unroll
  for (int dt = 0; dt < 8; dt++) {
    #pragma unroll
    for (int r = 0; r < 4; r++) {
      int qg = wq0 + lg * 4 + r;
      int d = dt * 16 + lr;
      ob[base + (size_t)qg * DD + d] = f2bf(o[dt][r] / lrow[r]);
    }
  }
}

// ---------------------------------------------------------------- launch
extern "C" void kernel_launch(void* const* d_in, const int* in_sizes, int n_in,
                              void* d_out, int out_size, void* d_ws,
                              size_t ws_size, hipStream_t stream) {
  const float* x    = (const float*)d_in[0];
  const float* Wq   = (const float*)d_in[1];
  const float* bq   = (const float*)d_in[2];
  const float* Wk   = (const float*)d_in[3];
  const float* bk   = (const float*)d_in[4];
  const float* Wv   = (const float*)d_in[5];
  const float* bv   = (const float*)d_in[6];
  const float* Wo   = (const float*)d_in[7];
  const float* bo   = (const float*)d_in[8];
  const float* ln1g = (const float*)d_in[9];
  const float* ln1b = (const float*)d_in[10];
  const float* ln2g = (const float*)d_in[11];
  const float* ln2b = (const float*)d_in[12];
  const float* W1   = (const float*)d_in[13];
  const float* b1   = (const float*)d_in[14];
  const float* W2   = (const float*)d_in[15];
  const float* b2   = (const float*)d_in[16];

  char* ws = (char*)d_ws;
  // Region W [0, 64MB): Wq/Wk/Wv/Wo bf16; later reused for W1b+W2b
  ushort* Wqb = (ushort*)(ws);
  ushort* Wkb = Wqb + (size_t)DD * DD;
  ushort* Wvb = Wkb + (size_t)DD * DD;
  ushort* Wob = Wvb + (size_t)DD * DD;
  ushort* W1b = (ushort*)(ws);                       // alias (after Wo GEMM)
  ushort* W2b = W1b + (size_t)D4 * DD;
  // Region Q [64MB, 128MB): q/k/v/attn_out bf16; later reused for gelu out
  ushort* qbf = (ushort*)(ws + 67108864);
  ushort* kbf = qbf + (size_t)MM * DD;
  ushort* vbf = kbf + (size_t)MM * DD;
  ushort* aob = vbf + (size_t)MM * DD;
  ushort* gb  = (ushort*)(ws + 67108864);            // alias (after Wo GEMM)
  // Region H [128MB, 160MB): h f32; later h2 f32
  float* hf  = (float*)(ws + 134217728);
  float* h2f = hf;                                   // alias (after Wo GEMM)
  // Region Hb [160MB, 176MB): h bf16; later h2 bf16
  ushort* hb  = (ushort*)(ws + 167772160);
  ushort* h2b = hb;                                  // alias (after QKV GEMMs)
  // Region H2 [176MB, 208MB): h + attn out (pre-LN2) f32
  float* h2in = (float*)(ws + 184549376);
  float* out  = (float*)d_out;

  dim3 blk(256);
  // 1. weight conversions for phase 1
  cvt_f32_bf16<<<DD * DD / 4 / 256, blk, 0, stream>>>(Wq, Wqb, DD * DD / 4);
  cvt_f32_bf16<<<DD * DD / 4 / 256, blk, 0, stream>>>(Wk, Wkb, DD * DD / 4);
  cvt_f32_bf16<<<DD * DD / 4 / 256, blk, 0, stream>>>(Wv, Wvb, DD * DD / 4);
  cvt_f32_bf16<<<DD * DD / 4 / 256, blk, 0, stream>>>(Wo, Wob, DD * DD / 4);
  // 2. LN1
  ln_rows<<<MM, blk, 0, stream>>>(x, ln1g, ln1b, hf, hb);
  // 3. QKV projections
  gemm_bt<true, false, false><<<512, blk, 0, stream>>>(hb, Wqb, bq, nullptr, qbf, MM, DD, DD);
  gemm_bt<true, false, false><<<512, blk, 0, stream>>>(hb, Wkb, bk, nullptr, kbf, MM, DD, DD);
  gemm_bt<true, false, false><<<512, blk, 0, stream>>>(hb, Wvb, bv, nullptr, vbf, MM, DD, DD);
  // 4. causal attention
  attn_fwd<<<BB * HH * (SS / 64), blk, 0, stream>>>(qbf, kbf, vbf, aob);
  // 5. output projection + residual (h)
  gemm_bt<false, false, true><<<512, blk, 0, stream>>>(aob, Wob, bo, hf, h2in, MM, DD, DD);
  // 6. LN2
  ln_rows<<<MM, blk, 0, stream>>>(h2in, ln2g, ln2b, h2f, h2b);
  // 7. MLP weight conversions (reuse region W)
  cvt_f32_bf16<<<D4 * DD / 4 / 256, blk, 0, stream>>>(W1, W1b, D4 * DD / 4);
  cvt_f32_bf16<<<D4 * DD / 4 / 256, blk, 0, stream>>>(W2, W2b, D4 * DD / 4);
  // 8. MLP up + GELU (reuse region Q)
  gemm_bt<true, true, false><<<2048, blk, 0, stream>>>(h2b, W1b, b1, nullptr, gb, MM, D4, DD);
  // 9. MLP down + residual (h2) -> out
  gemm_bt<false, false, true><<<512, blk, 0, stream>>>(gb, W2b, b2, h2f, out, MM, DD, D4);
}

// Round 2
// 814.443 us; speedup vs baseline: 1.2154x; 1.2154x over previous
//
#include <hip/hip_runtime.h>
#include <hip/hip_bf16.h>
#include <math.h>

// Problem constants
#define DD   2048
#define SS   2048
#define HH   16
#define HDIM 128
#define BB   2
#define MM   4096   // B*S rows
#define D4   8192

using bf16x8 = __attribute__((ext_vector_type(8))) short;
using f32x4  = __attribute__((ext_vector_type(4))) float;
using f32x16 = __attribute__((ext_vector_type(16))) float;

__device__ __forceinline__ ushort f2bf(float x) {
  uint u = __builtin_bit_cast(uint, x);
  u += 0x7FFFu + ((u >> 16) & 1u);   // round-to-nearest-even
  return (ushort)(u >> 16);
}

__device__ __forceinline__ float gelu_f(float v) {
  // jax.nn.gelu default (approximate=True, tanh form)
  float u = 0.7978845608028654f * (v + 0.044715f * v * v * v);
  float e = __expf(2.0f * u);
  float th = 1.0f - 2.0f / (e + 1.0f);   // robust tanh (inf-safe)
  return 0.5f * v * (1.0f + th);
}

__device__ __forceinline__ void gload_lds16(const void* g, void* l) {
  __builtin_amdgcn_global_load_lds(
      (const __attribute__((address_space(1))) void*)g,
      (__attribute__((address_space(3))) void*)l, 16, 0, 0);
}

// ---------------------------------------------------------------- f32 -> bf16
__global__ __launch_bounds__(256) void cvt_f32_bf16(
    const float* __restrict__ in, ushort* __restrict__ out, int n4) {
  int i = blockIdx.x * 256 + threadIdx.x;
  if (i >= n4) return;
  float4 v = ((const float4*)in)[i];
  ushort4 o;
  o.x = f2bf(v.x); o.y = f2bf(v.y); o.z = f2bf(v.z); o.w = f2bf(v.w);
  ((ushort4*)out)[i] = o;
}

// ---------------------------------------------------------------- LayerNorm
// one block (256 thr) per row of 2048; writes f32 and bf16 copies
__global__ __launch_bounds__(256) void ln_rows(
    const float* __restrict__ in, const float* __restrict__ gam,
    const float* __restrict__ bet, float* __restrict__ outf,
    ushort* __restrict__ outb) {
  int row = blockIdx.x;
  int t = threadIdx.x;
  const float4* r4 = (const float4*)(in + (size_t)row * DD);
  float4 v0 = r4[t], v1 = r4[t + 256];
  float s = v0.x + v0.y + v0.z + v0.w + v1.x + v1.y + v1.z + v1.w;
  __shared__ float redA[4], redB[4];
  #pragma unroll
  for (int off = 32; off >= 1; off >>= 1) s += __shfl_xor(s, off);
  if ((t & 63) == 0) redA[t >> 6] = s;
  __syncthreads();
  float mean = (redA[0] + redA[1] + redA[2] + redA[3]) * (1.0f / DD);
  float d0 = v0.x - mean, d1 = v0.y - mean, d2 = v0.z - mean, d3 = v0.w - mean;
  float d4 = v1.x - mean, d5 = v1.y - mean, d6 = v1.z - mean, d7 = v1.w - mean;
  float q = d0*d0 + d1*d1 + d2*d2 + d3*d3 + d4*d4 + d5*d5 + d6*d6 + d7*d7;
  #pragma unroll
  for (int off = 32; off >= 1; off >>= 1) q += __shfl_xor(q, off);
  if ((t & 63) == 0) redB[t >> 6] = q;
  __syncthreads();
  float var = (redB[0] + redB[1] + redB[2] + redB[3]) * (1.0f / DD);
  float rstd = rsqrtf(var + 1e-5f);
  const float4* g4 = (const float4*)gam;
  const float4* b4 = (const float4*)bet;
  float4 g0 = g4[t], g1 = g4[t + 256], bb0 = b4[t], bb1 = b4[t + 256];
  float4 y0, y1;
  y0.x = d0 * rstd * g0.x + bb0.x;  y0.y = d1 * rstd * g0.y + bb0.y;
  y0.z = d2 * rstd * g0.z + bb0.z;  y0.w = d3 * rstd * g0.w + bb0.w;
  y1.x = d4 * rstd * g1.x + bb1.x;  y1.y = d5 * rstd * g1.y + bb1.y;
  y1.z = d6 * rstd * g1.z + bb1.z;  y1.w = d7 * rstd * g1.w + bb1.w;
  float4* of4 = (float4*)(outf + (size_t)row * DD);
  of4[t] = y0; of4[t + 256] = y1;
  ushort4 u0, u1;
  u0.x = f2bf(y0.x); u0.y = f2bf(y0.y); u0.z = f2bf(y0.z); u0.w = f2bf(y0.w);
  u1.x = f2bf(y1.x); u1.y = f2bf(y1.y); u1.z = f2bf(y1.z); u1.w = f2bf(y1.w);
  ushort4* ob4 = (ushort4*)(outb + (size_t)row * DD);
  ob4[t] = u0; ob4[t + 256] = u1;
}

// ---------------------------------------------------------------- GEMM
// C[M,N] = A[M,K](bf16) @ Bt[N,K](bf16)^T + bias[N] (+res) (gelu)
// OMODE: 0 = f32 out, 1 = bf16 out, 2 = bf16 transposed-per-head (V^T) out
// 128x128 tile, BK=32, 4 waves (2x2 of 64x64). LDS src-swizzled for
// global_load_lds (chunk' = chunk ^ ((row>>1)&3)) -> 2-way-free frag reads.
template <int OMODE, bool GELU_, bool RES_>
__global__ __launch_bounds__(256) void gemm_bt(
    const ushort* __restrict__ A, const ushort* __restrict__ Bt,
    const float* __restrict__ bias, const float* __restrict__ res,
    void* __restrict__ Cout, int M, int N, int K) {
  __shared__ ushort As[128 * 32];
  __shared__ ushort Bs[128 * 32];
  const int nbm = M >> 7;
  int bm = blockIdx.x % nbm, bn = blockIdx.x / nbm;
  int m0 = bm << 7, n0 = bn << 7;
  int t = threadIdx.x, lane = t & 63, w = t >> 6;
  int wr = (w >> 1) * 64, wc = (w & 1) * 64;
  int lr = lane & 15, lg = lane >> 4;

  f32x4 acc[4][4] = {};
  int srow = t >> 2;
  int schunk = t & 3;
  int sc = (schunk ^ ((srow >> 1) & 3)) * 8;   // swizzled k-offset (elements)

  for (int k0 = 0; k0 < K; k0 += 32) {
    const ushort* Ab = A + (size_t)(m0 + srow) * K + k0;
    const ushort* Bb = Bt + (size_t)(n0 + srow) * K + k0;
    gload_lds16(Ab + sc, &As[t * 8]);
    gload_lds16(Ab + (size_t)64 * K + sc, &As[2048 + t * 8]);
    gload_lds16(Bb + sc, &Bs[t * 8]);
    gload_lds16(Bb + (size_t)64 * K + sc, &Bs[2048 + t * 8]);
    __syncthreads();
    bf16x8 af[4], bf_[4];
    #pragma unroll
    for (int mi = 0; mi < 4; mi++) {
      int row = wr + mi * 16 + lr;
      af[mi] = *(const bf16x8*)&As[row * 32 + ((lg ^ ((row >> 1) & 3)) << 3)];
    }
    #pragma unroll
    for (int ni = 0; ni < 4; ni++) {
      int row = wc + ni * 16 + lr;
      bf_[ni] = *(const bf16x8*)&Bs[row * 32 + ((lg ^ ((row >> 1) & 3)) << 3)];
    }
    #pragma unroll
    for (int mi = 0; mi < 4; mi++)
      #pragma unroll
      for (int ni = 0; ni < 4; ni++)
        acc[mi][ni] = __builtin_amdgcn_mfma_f32_16x16x32_bf16(
            af[mi], bf_[ni], acc[mi][ni], 0, 0, 0);
    __syncthreads();
  }

  float bv[4];
  #pragma unroll
  for (int ni = 0; ni < 4; ni++) bv[ni] = bias[n0 + wc + ni * 16 + lr];

  if (OMODE == 2) {
    // V^T epilogue: write vT[(b*16+h)][d][s] ushort4 along s (4 consec m)
    #pragma unroll
    for (int mi = 0; mi < 4; mi++) {
      int mg = m0 + wr + mi * 16 + lg * 4;
      int bb_ = mg >> 11, sb = mg & 2047;
      #pragma unroll
      for (int ni = 0; ni < 4; ni++) {
        int n = n0 + wc + ni * 16 + lr;
        ushort4 u4;
        u4.x = f2bf(acc[mi][ni][0] + bv[ni]);
        u4.y = f2bf(acc[mi][ni][1] + bv[ni]);
        u4.z = f2bf(acc[mi][ni][2] + bv[ni]);
        u4.w = f2bf(acc[mi][ni][3] + bv[ni]);
        size_t idx = ((size_t)((bb_ << 4) | (n >> 7)) * 128 + (n & 127)) * 2048
                     + sb;
        *(ushort4*)&((ushort*)Cout)[idx] = u4;
      }
    }
    return;
  }

  #pragma unroll
  for (int mi = 0; mi < 4; mi++) {
    #pragma unroll
    for (int r = 0; r < 4; r++) {
      int m = m0 + wr + mi * 16 + lg * 4 + r;
      #pragma unroll
      for (int ni = 0; ni < 4; ni++) {
        int n = n0 + wc + ni * 16 + lr;
        size_t idx = (size_t)m * N + n;
        float v = acc[mi][ni][r] + bv[ni];
        if (RES_) v += res[idx];
        if (GELU_) v = gelu_f(v);
        if (OMODE == 1) ((ushort*)Cout)[idx] = f2bf(v);
        else            ((float*)Cout)[idx] = v;
      }
    }
  }
}

// ---------------------------------------------------------------- Attention
// Swapped-operand causal flash attention, mfma_f32_32x32x16_bf16.
// Block = 4 waves x 32 q-rows = 128 q-rows. Grid = 32 bh * 16 qtiles = 512.
// Per KV-64 tile: S^T = K·Q^T (softmax lane-local, col=q=lane&31),
// O^T += V^T·P^T (V pre-transposed in global by the V-projection GEMM).
// K/V staged with swizzled-source global_load_lds; P via per-wave swizzled LDS.
__global__ __launch_bounds__(256) void attn_fwd(
    const ushort* __restrict__ qb, const ushort* __restrict__ kb,
    const ushort* __restrict__ vTb, ushort* __restrict__ ob) {
  __shared__ ushort Ks[64 * 128];    // [kv][hd], chunk' = chunk ^ (kv&15)
  __shared__ ushort Vs[128 * 64];    // [d][kv],  chunk' = chunk ^ (d&7)
  __shared__ ushort Ps[4][32 * 64];  // per wave [q][kv], chunk' = chunk ^ (q&7)

  int blk = blockIdx.x;
  int i15 = blk & 15;
  int qt = (blk & 256) ? i15 : 15 - i15;   // complementary pairing across CUs
  int bh = blk >> 4;                        // 0..31
  int b = bh >> 4, h = bh & 15;
  int q0 = qt << 7;
  int t = threadIdx.x, lane = t & 63, w = t >> 6;
  int l31 = lane & 31, hi = lane >> 5;
  const size_t base = (size_t)b * SS * DD + (size_t)h * HDIM;
  const ushort* qp = qb + base;
  const ushort* kp = kb + base;
  const ushort* vp = vTb + (size_t)bh * HDIM * SS;   // V^T: [d][s]
  int wq0 = q0 + w * 32;
  int qg = wq0 + l31;                       // this lane's q row (seq pos)

  bf16x8 qf[8];
  #pragma unroll
  for (int kk = 0; kk < 8; kk++)
    qf[kk] = *(const bf16x8*)(qp + (size_t)qg * DD + kk * 16 + hi * 8);

  f32x16 o[4] = {};
  float mu = -1e30f, lrow = 0.f;
  const float csc = 0.08838834764831845f * 1.4426950408889634f; // scale*log2e

  int nIter = 2 * qt + 2;
  for (int it = 0; it < nIter; ++it) {
    int kv0 = it * 64;
    // ---- stage K [64][128] and V^T [128][64] via global_load_lds w16
    #pragma unroll
    for (int ii = 0; ii < 4; ii++) {
      int chunk = ii * 256 + t;            // 1024 chunks
      int row = chunk >> 4, cc = chunk & 15;
      gload_lds16(kp + (size_t)(kv0 + row) * DD + ((cc ^ (row & 15)) << 3),
                  &Ks[chunk * 8]);
    }
    #pragma unroll
    for (int ii = 0; ii < 4; ii++) {
      int chunk = ii * 256 + t;            // 1024 chunks
      int row = chunk >> 3, cc = chunk & 7;
      gload_lds16(vp + (size_t)row * SS + kv0 + ((cc ^ (row & 7)) << 3),
                  &Vs[chunk * 8]);
    }
    __syncthreads();

    if (kv0 <= wq0 + 31) {
      // ---- S^T[64 kv][32 q] = K·Q^T
      f32x16 s2[2] = {};
      #pragma unroll
      for (int nt = 0; nt < 2; nt++) {
        int row = nt * 32 + l31;
        #pragma unroll
        for (int kk = 0; kk < 8; kk++) {
          bf16x8 kf = *(const bf16x8*)
              &Ks[row * 128 + (((kk * 2 + hi) ^ (row & 15)) << 3)];
          s2[nt] = __builtin_amdgcn_mfma_f32_32x32x16_bf16(kf, qf[kk], s2[nt],
                                                           0, 0, 0);
        }
      }
      // ---- mask + online softmax (lane-local row, partner = lane^32)
      float mx = -3e38f;
      #pragma unroll
      for (int nt = 0; nt < 2; nt++) {
        #pragma unroll
        for (int r = 0; r < 16; r++) {
          int kvl = nt * 32 + (r & 3) + 8 * (r >> 2) + 4 * hi;
          float u = (kv0 + kvl > qg) ? -3e38f : s2[nt][r] * csc;
          s2[nt][r] = u;
          mx = fmaxf(mx, u);
        }
      }
      mx = fmaxf(mx, __shfl_xor(mx, 32));
      float mnew = fmaxf(mu, mx);
      float fr = exp2f(mu - mnew);
      mu = mnew;
      float sum = 0.f;
      #pragma unroll
      for (int nt = 0; nt < 2; nt++)
        #pragma unroll
        for (int r = 0; r < 16; r++) {
          float p = exp2f(s2[nt][r] - mnew);
          s2[nt][r] = p;
          sum += p;
        }
      sum += __shfl_xor(sum, 32);
      lrow = lrow * fr + sum;
      #pragma unroll
      for (int dt = 0; dt < 4; dt++)
        #pragma unroll
        for (int r = 0; r < 16; r++) o[dt][r] *= fr;
      // ---- pack P -> Ps[q][kv] (b64 stores, XOR-swizzled chunks)
      #pragma unroll
      for (int nt = 0; nt < 2; nt++) {
        #pragma unroll
        for (int g2 = 0; g2 < 4; g2++) {
          ushort4 u4;
          u4.x = f2bf(s2[nt][g2 * 4 + 0]);
          u4.y = f2bf(s2[nt][g2 * 4 + 1]);
          u4.z = f2bf(s2[nt][g2 * 4 + 2]);
          u4.w = f2bf(s2[nt][g2 * 4 + 3]);
          int cp = (nt * 4 + g2) ^ (l31 & 7);
          *(ushort4*)&Ps[w][l31 * 64 + cp * 8 + hi * 4] = u4;
        }
      }
      asm volatile("s_waitcnt lgkmcnt(0)" ::: "memory");
      // ---- O^T[128 d][32 q] += V^T·P^T
      #pragma unroll
      for (int kk = 0; kk < 4; kk++) {
        bf16x8 pf = *(const bf16x8*)
            &Ps[w][l31 * 64 + (((kk * 2 + hi) ^ (l31 & 7)) << 3)];
        #pragma unroll
        for (int dt = 0; dt < 4; dt++) {
          int drow = dt * 32 + l31;
          bf16x8 vf = *(const bf16x8*)
              &Vs[drow * 64 + (((kk * 2 + hi) ^ (drow & 7)) << 3)];
          o[dt] = __builtin_amdgcn_mfma_f32_32x32x16_bf16(vf, pf, o[dt],
                                                          0, 0, 0);
        }
      }
    }
    __syncthreads();
  }

  float inv = 1.0f / lrow;
  #pragma unroll
  for (int dt = 0; dt < 4; dt++) {
    #pragma unroll
    for (int g2 = 0; g2 < 4; g2++) {
      ushort4 u4;
      u4.x = f2bf(o[dt][g2 * 4 + 0] * inv);
      u4.y = f2bf(o[dt][g2 * 4 + 1] * inv);
      u4.z = f2bf(o[dt][g2 * 4 + 2] * inv);
      u4.w = f2bf(o[dt][g2 * 4 + 3] * inv);
      int d = dt * 32 + 8 * g2 + 4 * hi;
      *(ushort4*)&ob[base + (size_t)qg * DD + d] = u4;
    }
  }
}

// ---------------------------------------------------------------- launch
extern "C" void kernel_launch(void* const* d_in, const int* in_sizes, int n_in,
                              void* d_out, int out_size, void* d_ws,
                              size_t ws_size, hipStream_t stream) {
  const float* x    = (const float*)d_in[0];
  const float* Wq   = (const float*)d_in[1];
  const float* bq   = (const float*)d_in[2];
  const float* Wk   = (const float*)d_in[3];
  const float* bk   = (const float*)d_in[4];
  const float* Wv   = (const float*)d_in[5];
  const float* bv   = (const float*)d_in[6];
  const float* Wo   = (const float*)d_in[7];
  const float* bo   = (const float*)d_in[8];
  const float* ln1g = (const float*)d_in[9];
  const float* ln1b = (const float*)d_in[10];
  const float* ln2g = (const float*)d_in[11];
  const float* ln2b = (const float*)d_in[12];
  const float* W1   = (const float*)d_in[13];
  const float* b1   = (const float*)d_in[14];
  const float* W2   = (const float*)d_in[15];
  const float* b2   = (const float*)d_in[16];

  char* ws = (char*)d_ws;
  // Region W [0, 64MB): Wq/Wk/Wv/Wo bf16; later reused for W1b/W2b
  ushort* Wqb = (ushort*)(ws);
  ushort* Wkb = Wqb + (size_t)DD * DD;
  ushort* Wvb = Wkb + (size_t)DD * DD;
  ushort* Wob = Wvb + (size_t)DD * DD;
  ushort* W1b = (ushort*)(ws);                       // alias (after Wo GEMM)
  ushort* W2b = W1b + (size_t)D4 * DD;
  // Region Q [64MB, 128MB): q/k/vT/attn_out bf16; later reused for gelu out
  ushort* qbf = (ushort*)(ws + 67108864);
  ushort* kbf = qbf + (size_t)MM * DD;
  ushort* vTt = kbf + (size_t)MM * DD;               // V^T: [bh][d][s]
  ushort* aob = vTt + (size_t)MM * DD;
  ushort* gb  = (ushort*)(ws + 67108864);            // alias (after Wo GEMM)
  // Region H [128MB, 160MB): h f32; later h2 f32
  float* hf  = (float*)(ws + 134217728);
  float* h2f = hf;                                   // alias (after Wo GEMM)
  // Region Hb [160MB, 176MB): h bf16; later h2 bf16
  ushort* hb  = (ushort*)(ws + 167772160);
  ushort* h2b = hb;                                  // alias (after QKV GEMMs)
  // Region H2 [176MB, 208MB): h + attn out (pre-LN2) f32
  float* h2in = (float*)(ws + 184549376);
  float* out  = (float*)d_out;

  dim3 blk(256);
  // 1. weight conversions for phase 1
  cvt_f32_bf16<<<DD * DD / 4 / 256, blk, 0, stream>>>(Wq, Wqb, DD * DD / 4);
  cvt_f32_bf16<<<DD * DD / 4 / 256, blk, 0, stream>>>(Wk, Wkb, DD * DD / 4);
  cvt_f32_bf16<<<DD * DD / 4 / 256, blk, 0, stream>>>(Wv, Wvb, DD * DD / 4);
  cvt_f32_bf16<<<DD * DD / 4 / 256, blk, 0, stream>>>(Wo, Wob, DD * DD / 4);
  // 2. LN1
  ln_rows<<<MM, blk, 0, stream>>>(x, ln1g, ln1b, hf, hb);
  // 3. QKV projections (V written transposed per-head)
  gemm_bt<1, false, false><<<512, blk, 0, stream>>>(hb, Wqb, bq, nullptr, qbf, MM, DD, DD);
  gemm_bt<1, false, false><<<512, blk, 0, stream>>>(hb, Wkb, bk, nullptr, kbf, MM, DD, DD);
  gemm_bt<2, false, false><<<512, blk, 0, stream>>>(hb, Wvb, bv, nullptr, vTt, MM, DD, DD);
  // 4. causal attention (swapped-operand, 32x32 MFMA)
  attn_fwd<<<512, blk, 0, stream>>>(qbf, kbf, vTt, aob);
  // 5. output projection + residual (h)
  gemm_bt<0, false, true><<<512, blk, 0, stream>>>(aob, Wob, bo, hf, h2in, MM, DD, DD);
  // 6. LN2
  ln_rows<<<MM, blk, 0, stream>>>(h2in, ln2g, ln2b, h2f, h2b);
  // 7. MLP weight conversions (reuse region W)
  cvt_f32_bf16<<<D4 * DD / 4 / 256, blk, 0, stream>>>(W1, W1b, D4 * DD / 4);
  cvt_f32_bf16<<<D4 * DD / 4 / 256, blk, 0, stream>>>(W2, W2b, D4 * DD / 4);
  // 8. MLP up + GELU (reuse region Q)
  gemm_bt<1, true, false><<<2048, blk, 0, stream>>>(h2b, W1b, b1, nullptr, gb, MM, D4, DD);
  // 9. MLP down + residual (h2) -> out
  gemm_bt<0, false, true><<<512, blk, 0, stream>>>(gb, W2b, b2, h2f, out, MM, DD, D4);
}

// Round 3
// 673.820 us; speedup vs baseline: 1.4690x; 1.2087x over previous
//
#include <hip/hip_runtime.h>
#include <hip/hip_bf16.h>
#include <math.h>

// Problem constants
#define DD   2048
#define SS   2048
#define HH   16
#define HDIM 128
#define BB   2
#define MM   4096   // B*S rows
#define D4   8192

using bf16x8 = __attribute__((ext_vector_type(8))) short;
using f32x4  = __attribute__((ext_vector_type(4))) float;
using f32x16 = __attribute__((ext_vector_type(16))) float;

__device__ __forceinline__ ushort f2bf(float x) {
  uint u = __builtin_bit_cast(uint, x);
  u += 0x7FFFu + ((u >> 16) & 1u);   // round-to-nearest-even
  return (ushort)(u >> 16);
}

__device__ __forceinline__ float gelu_f(float v) {
  // jax.nn.gelu default (approximate=True, tanh form)
  float u = 0.7978845608028654f * (v + 0.044715f * v * v * v);
  float e = __expf(2.0f * u);
  float th = 1.0f - 2.0f / (e + 1.0f);   // robust tanh (inf-safe)
  return 0.5f * v * (1.0f + th);
}

__device__ __forceinline__ void gload_lds16(const void* g, void* l) {
  __builtin_amdgcn_global_load_lds(
      (const __attribute__((address_space(1))) void*)g,
      (__attribute__((address_space(3))) void*)l, 16, 0, 0);
}

// ---------------------------------------------------------------- f32 -> bf16
__global__ __launch_bounds__(256) void cvt_f32_bf16(
    const float* __restrict__ in, ushort* __restrict__ out, int n4) {
  int i = blockIdx.x * 256 + threadIdx.x;
  if (i >= n4) return;
  float4 v = ((const float4*)in)[i];
  ushort4 o;
  o.x = f2bf(v.x); o.y = f2bf(v.y); o.z = f2bf(v.z); o.w = f2bf(v.w);
  ((ushort4*)out)[i] = o;
}

// ---------------------------------------------------------------- LayerNorm
__global__ __launch_bounds__(256) void ln_rows(
    const float* __restrict__ in, const float* __restrict__ gam,
    const float* __restrict__ bet, float* __restrict__ outf,
    ushort* __restrict__ outb) {
  int row = blockIdx.x;
  int t = threadIdx.x;
  const float4* r4 = (const float4*)(in + (size_t)row * DD);
  float4 v0 = r4[t], v1 = r4[t + 256];
  float s = v0.x + v0.y + v0.z + v0.w + v1.x + v1.y + v1.z + v1.w;
  __shared__ float redA[4], redB[4];
  #pragma unroll
  for (int off = 32; off >= 1; off >>= 1) s += __shfl_xor(s, off);
  if ((t & 63) == 0) redA[t >> 6] = s;
  __syncthreads();
  float mean = (redA[0] + redA[1] + redA[2] + redA[3]) * (1.0f / DD);
  float d0 = v0.x - mean, d1 = v0.y - mean, d2 = v0.z - mean, d3 = v0.w - mean;
  float d4 = v1.x - mean, d5 = v1.y - mean, d6 = v1.z - mean, d7 = v1.w - mean;
  float q = d0*d0 + d1*d1 + d2*d2 + d3*d3 + d4*d4 + d5*d5 + d6*d6 + d7*d7;
  #pragma unroll
  for (int off = 32; off >= 1; off >>= 1) q += __shfl_xor(q, off);
  if ((t & 63) == 0) redB[t >> 6] = q;
  __syncthreads();
  float var = (redB[0] + redB[1] + redB[2] + redB[3]) * (1.0f / DD);
  float rstd = rsqrtf(var + 1e-5f);
  const float4* g4 = (const float4*)gam;
  const float4* b4 = (const float4*)bet;
  float4 g0 = g4[t], g1 = g4[t + 256], bb0 = b4[t], bb1 = b4[t + 256];
  float4 y0, y1;
  y0.x = d0 * rstd * g0.x + bb0.x;  y0.y = d1 * rstd * g0.y + bb0.y;
  y0.z = d2 * rstd * g0.z + bb0.z;  y0.w = d3 * rstd * g0.w + bb0.w;
  y1.x = d4 * rstd * g1.x + bb1.x;  y1.y = d5 * rstd * g1.y + bb1.y;
  y1.z = d6 * rstd * g1.z + bb1.z;  y1.w = d7 * rstd * g1.w + bb1.w;
  float4* of4 = (float4*)(outf + (size_t)row * DD);
  of4[t] = y0; of4[t + 256] = y1;
  ushort4 u0, u1;
  u0.x = f2bf(y0.x); u0.y = f2bf(y0.y); u0.z = f2bf(y0.z); u0.w = f2bf(y0.w);
  u1.x = f2bf(y1.x); u1.y = f2bf(y1.y); u1.z = f2bf(y1.z); u1.w = f2bf(y1.w);
  ushort4* ob4 = (ushort4*)(outb + (size_t)row * DD);
  ob4[t] = u0; ob4[t + 256] = u1;
}

// ---------------------------------------------------------------- GEMM v2
// C[M,N] = A[M,K](bf16) @ Bt[N,K](bf16)^T + bias[N] (+res) (gelu)
// OMODE: 0 = f32 out, 1 = bf16 out, 2 = bf16 transposed-per-head (V^T) out
// Tile 256x128, BK=64, 512 thr (8 waves 2Mx4N, 128x32/wave).
// TRIPLE-buffered LDS (3 x 48KB, dynamic): one counted s_waitcnt vmcnt(6)
// + one raw s_barrier per K-tile; stage(t+2) issued after the barrier.
// Chunk-XOR swizzle (^(row&7)) on both stage-source and frag-read.
template <int OMODE, bool GELU_, bool RES_>
__global__ __launch_bounds__(512, 2) void gemm2(
    const ushort* __restrict__ A, const ushort* __restrict__ Bt,
    const float* __restrict__ bias, const float* __restrict__ res,
    void* __restrict__ Cout, int M, int N, int K) {
  extern __shared__ __align__(16) ushort smem[];   // 3 * (16384 + 8192)
  const int nbm = M >> 8, nbn = N >> 7;
  const int nwg = nbm * nbn;
  int wg = blockIdx.x;
  int wg2 = (wg & 7) * (nwg >> 3) + (wg >> 3);     // bijective XCD swizzle
  int bm = wg2 % nbm, bn = wg2 / nbm;
  int m0 = bm << 8, n0 = bn << 7;
  int t = threadIdx.x, lane = t & 63, w = t >> 6;
  int wm = w >> 2, wn = w & 3;
  int lr = lane & 15, lg = lane >> 4;

  auto stage = [&](int kt, int slot) {
    int k0 = kt << 6;
    ushort* lA = smem + slot * 24576;
    ushort* lB = lA + 16384;
    #pragma unroll
    for (int r = 0; r < 4; r++) {
      int idx = (r << 9) + t;
      int row = idx >> 3, ch = idx & 7;
      gload_lds16(A + (size_t)(m0 + row) * K + k0 + ((ch ^ (row & 7)) << 3),
                  lA + idx * 8);
    }
    #pragma unroll
    for (int r = 0; r < 2; r++) {
      int idx = (r << 9) + t;
      int row = idx >> 3, ch = idx & 7;
      gload_lds16(Bt + (size_t)(n0 + row) * K + k0 + ((ch ^ (row & 7)) << 3),
                  lB + idx * 8);
    }
  };

  f32x4 acc[8][2] = {};
  const int NT = K >> 6;
  stage(0, 0);
  stage(1, 1);
  int slot = 0;
  for (int kt = 0; kt < NT; ++kt) {
    __builtin_amdgcn_sched_barrier(0);   // pin compute(kt-1) above the barrier
    if (kt + 1 < NT)
      asm volatile("s_waitcnt vmcnt(6) lgkmcnt(0)" ::: "memory");
    else
      asm volatile("s_waitcnt vmcnt(0) lgkmcnt(0)" ::: "memory");
    __builtin_amdgcn_s_barrier();        // raw: no vmcnt drain
    __builtin_amdgcn_sched_barrier(0);
    if (kt + 2 < NT) {
      int s2 = slot + 2; if (s2 >= 3) s2 -= 3;
      stage(kt + 2, s2);                 // slot freed by the barrier above
    }
    const ushort* lA = smem + slot * 24576;
    const ushort* lB = lA + 16384;
    bf16x8 af[8][2], bfr[2][2];
    #pragma unroll
    for (int mi = 0; mi < 8; mi++) {
      int row = wm * 128 + mi * 16 + lr;
      #pragma unroll
      for (int ks = 0; ks < 2; ks++)
        af[mi][ks] = *(const bf16x8*)
            &lA[row * 64 + (((ks * 4 + lg) ^ (row & 7)) << 3)];
    }
    #pragma unroll
    for (int ni = 0; ni < 2; ni++) {
      int row = wn * 32 + ni * 16 + lr;
      #pragma unroll
      for (int ks = 0; ks < 2; ks++)
        bfr[ni][ks] = *(const bf16x8*)
            &lB[row * 64 + (((ks * 4 + lg) ^ (row & 7)) << 3)];
    }
    __builtin_amdgcn_s_setprio(1);
    #pragma unroll
    for (int ks = 0; ks < 2; ks++)
      #pragma unroll
      for (int mi = 0; mi < 8; mi++)
        #pragma unroll
        for (int ni = 0; ni < 2; ni++)
          acc[mi][ni] = __builtin_amdgcn_mfma_f32_16x16x32_bf16(
              af[mi][ks], bfr[ni][ks], acc[mi][ni], 0, 0, 0);
    __builtin_amdgcn_s_setprio(0);
    slot = (slot + 1 == 3) ? 0 : slot + 1;
  }

  float bv[2];
  #pragma unroll
  for (int ni = 0; ni < 2; ni++) bv[ni] = bias[n0 + wn * 32 + ni * 16 + lr];

  if (OMODE == 2) {
    // V^T epilogue: write vT[(b*16+h)][d][s] ushort4 along s (4 consec m)
    #pragma unroll
    for (int mi = 0; mi < 8; mi++) {
      int mg = m0 + wm * 128 + mi * 16 + lg * 4;
      int bb_ = mg >> 11, sb = mg & 2047;
      #pragma unroll
      for (int ni = 0; ni < 2; ni++) {
        int n = n0 + wn * 32 + ni * 16 + lr;
        ushort4 u4;
        u4.x = f2bf(acc[mi][ni][0] + bv[ni]);
        u4.y = f2bf(acc[mi][ni][1] + bv[ni]);
        u4.z = f2bf(acc[mi][ni][2] + bv[ni]);
        u4.w = f2bf(acc[mi][ni][3] + bv[ni]);
        size_t idx = ((size_t)((bb_ << 4) | (n >> 7)) * 128 + (n & 127)) * 2048
                     + sb;
        *(ushort4*)&((ushort*)Cout)[idx] = u4;
      }
    }
    return;
  }

  #pragma unroll
  for (int mi = 0; mi < 8; mi++) {
    #pragma unroll
    for (int r = 0; r < 4; r++) {
      int m = m0 + wm * 128 + mi * 16 + lg * 4 + r;
      #pragma unroll
      for (int ni = 0; ni < 2; ni++) {
        int n = n0 + wn * 32 + ni * 16 + lr;
        size_t idx = (size_t)m * N + n;
        float v = acc[mi][ni][r] + bv[ni];
        if (RES_) v += res[idx];
        if (GELU_) v = gelu_f(v);
        if (OMODE == 1) ((ushort*)Cout)[idx] = f2bf(v);
        else            ((float*)Cout)[idx] = v;
      }
    }
  }
}

// ---------------------------------------------------------------- Attention
// Swapped-operand causal flash attention, mfma_f32_32x32x16_bf16.
__global__ __launch_bounds__(256) void attn_fwd(
    const ushort* __restrict__ qb, const ushort* __restrict__ kb,
    const ushort* __restrict__ vTb, ushort* __restrict__ ob) {
  __shared__ ushort Ks[64 * 128];    // [kv][hd], chunk' = chunk ^ (kv&15)
  __shared__ ushort Vs[128 * 64];    // [d][kv],  chunk' = chunk ^ (d&7)
  __shared__ ushort Ps[4][32 * 64];  // per wave [q][kv], chunk' = chunk ^ (q&7)

  int blk = blockIdx.x;
  int i15 = blk & 15;
  int qt = (blk & 256) ? i15 : 15 - i15;   // complementary pairing across CUs
  int bh = blk >> 4;                        // 0..31
  int b = bh >> 4, h = bh & 15;
  int q0 = qt << 7;
  int t = threadIdx.x, lane = t & 63, w = t >> 6;
  int l31 = lane & 31, hi = lane >> 5;
  const size_t base = (size_t)b * SS * DD + (size_t)h * HDIM;
  const ushort* qp = qb + base;
  const ushort* kp = kb + base;
  const ushort* vp = vTb + (size_t)bh * HDIM * SS;   // V^T: [d][s]
  int wq0 = q0 + w * 32;
  int qg = wq0 + l31;

  bf16x8 qf[8];
  #pragma unroll
  for (int kk = 0; kk < 8; kk++)
    qf[kk] = *(const bf16x8*)(qp + (size_t)qg * DD + kk * 16 + hi * 8);

  f32x16 o[4] = {};
  float mu = -1e30f, lrow = 0.f;
  const float csc = 0.08838834764831845f * 1.4426950408889634f; // scale*log2e

  int nIter = 2 * qt + 2;
  for (int it = 0; it < nIter; ++it) {
    int kv0 = it * 64;
    #pragma unroll
    for (int ii = 0; ii < 4; ii++) {
      int chunk = ii * 256 + t;
      int row = chunk >> 4, cc = chunk & 15;
      gload_lds16(kp + (size_t)(kv0 + row) * DD + ((cc ^ (row & 15)) << 3),
                  &Ks[chunk * 8]);
    }
    #pragma unroll
    for (int ii = 0; ii < 4; ii++) {
      int chunk = ii * 256 + t;
      int row = chunk >> 3, cc = chunk & 7;
      gload_lds16(vp + (size_t)row * SS + kv0 + ((cc ^ (row & 7)) << 3),
                  &Vs[chunk * 8]);
    }
    __syncthreads();

    if (kv0 <= wq0 + 31) {
      f32x16 s2[2] = {};
      #pragma unroll
      for (int nt = 0; nt < 2; nt++) {
        int row = nt * 32 + l31;
        #pragma unroll
        for (int kk = 0; kk < 8; kk++) {
          bf16x8 kf = *(const bf16x8*)
              &Ks[row * 128 + (((kk * 2 + hi) ^ (row & 15)) << 3)];
          s2[nt] = __builtin_amdgcn_mfma_f32_32x32x16_bf16(kf, qf[kk], s2[nt],
                                                           0, 0, 0);
        }
      }
      float mx = -3e38f;
      #pragma unroll
      for (int nt = 0; nt < 2; nt++) {
        #pragma unroll
        for (int r = 0; r < 16; r++) {
          int kvl = nt * 32 + (r & 3) + 8 * (r >> 2) + 4 * hi;
          float u = (kv0 + kvl > qg) ? -3e38f : s2[nt][r] * csc;
          s2[nt][r] = u;
          mx = fmaxf(mx, u);
        }
      }
      mx = fmaxf(mx, __shfl_xor(mx, 32));
      float mnew = fmaxf(mu, mx);
      float fr = exp2f(mu - mnew);
      mu = mnew;
      float sum = 0.f;
      #pragma unroll
      for (int nt = 0; nt < 2; nt++)
        #pragma unroll
        for (int r = 0; r < 16; r++) {
          float p = exp2f(s2[nt][r] - mnew);
          s2[nt][r] = p;
          sum += p;
        }
      sum += __shfl_xor(sum, 32);
      lrow = lrow * fr + sum;
      #pragma unroll
      for (int dt = 0; dt < 4; dt++)
        #pragma unroll
        for (int r = 0; r < 16; r++) o[dt][r] *= fr;
      #pragma unroll
      for (int nt = 0; nt < 2; nt++) {
        #pragma unroll
        for (int g2 = 0; g2 < 4; g2++) {
          ushort4 u4;
          u4.x = f2bf(s2[nt][g2 * 4 + 0]);
          u4.y = f2bf(s2[nt][g2 * 4 + 1]);
          u4.z = f2bf(s2[nt][g2 * 4 + 2]);
          u4.w = f2bf(s2[nt][g2 * 4 + 3]);
          int cp = (nt * 4 + g2) ^ (l31 & 7);
          *(ushort4*)&Ps[w][l31 * 64 + cp * 8 + hi * 4] = u4;
        }
      }
      asm volatile("s_waitcnt lgkmcnt(0)" ::: "memory");
      #pragma unroll
      for (int kk = 0; kk < 4; kk++) {
        bf16x8 pf = *(const bf16x8*)
            &Ps[w][l31 * 64 + (((kk * 2 + hi) ^ (l31 & 7)) << 3)];
        #pragma unroll
        for (int dt = 0; dt < 4; dt++) {
          int drow = dt * 32 + l31;
          bf16x8 vf = *(const bf16x8*)
              &Vs[drow * 64 + (((kk * 2 + hi) ^ (drow & 7)) << 3)];
          o[dt] = __builtin_amdgcn_mfma_f32_32x32x16_bf16(vf, pf, o[dt],
                                                          0, 0, 0);
        }
      }
    }
    __syncthreads();
  }

  float inv = 1.0f / lrow;
  #pragma unroll
  for (int dt = 0; dt < 4; dt++) {
    #pragma unroll
    for (int g2 = 0; g2 < 4; g2++) {
      ushort4 u4;
      u4.x = f2bf(o[dt][g2 * 4 + 0] * inv);
      u4.y = f2bf(o[dt][g2 * 4 + 1] * inv);
      u4.z = f2bf(o[dt][g2 * 4 + 2] * inv);
      u4.w = f2bf(o[dt][g2 * 4 + 3] * inv);
      int d = dt * 32 + 8 * g2 + 4 * hi;
      *(ushort4*)&ob[base + (size_t)qg * DD + d] = u4;
    }
  }
}

// ---------------------------------------------------------------- launch
extern "C" void kernel_launch(void* const* d_in, const int* in_sizes, int n_in,
                              void* d_out, int out_size, void* d_ws,
                              size_t ws_size, hipStream_t stream) {
  const float* x    = (const float*)d_in[0];
  const float* Wq   = (const float*)d_in[1];
  const float* bq   = (const float*)d_in[2];
  const float* Wk   = (const float*)d_in[3];
  const float* bk   = (const float*)d_in[4];
  const float* Wv   = (const float*)d_in[5];
  const float* bv   = (const float*)d_in[6];
  const float* Wo   = (const float*)d_in[7];
  const float* bo   = (const float*)d_in[8];
  const float* ln1g = (const float*)d_in[9];
  const float* ln1b = (const float*)d_in[10];
  const float* ln2g = (const float*)d_in[11];
  const float* ln2b = (const float*)d_in[12];
  const float* W1   = (const float*)d_in[13];
  const float* b1   = (const float*)d_in[14];
  const float* W2   = (const float*)d_in[15];
  const float* b2   = (const float*)d_in[16];

  char* ws = (char*)d_ws;
  ushort* Wqb = (ushort*)(ws);
  ushort* Wkb = Wqb + (size_t)DD * DD;
  ushort* Wvb = Wkb + (size_t)DD * DD;
  ushort* Wob = Wvb + (size_t)DD * DD;
  ushort* W1b = (ushort*)(ws);                       // alias (after Wo GEMM)
  ushort* W2b = W1b + (size_t)D4 * DD;
  ushort* qbf = (ushort*)(ws + 67108864);
  ushort* kbf = qbf + (size_t)MM * DD;
  ushort* vTt = kbf + (size_t)MM * DD;               // V^T: [bh][d][s]
  ushort* aob = vTt + (size_t)MM * DD;
  ushort* gb  = (ushort*)(ws + 67108864);            // alias (after Wo GEMM)
  float* hf  = (float*)(ws + 134217728);
  float* h2f = hf;                                   // alias (after Wo GEMM)
  ushort* hb  = (ushort*)(ws + 167772160);
  ushort* h2b = hb;                                  // alias (after QKV GEMMs)
  float* h2in = (float*)(ws + 184549376);
  float* out  = (float*)d_out;

  const int LDSB = 147456;
  hipFuncSetAttribute((const void*)gemm2<1, false, false>,
                      hipFuncAttributeMaxDynamicSharedMemorySize, LDSB);
  hipFuncSetAttribute((const void*)gemm2<2, false, false>,
                      hipFuncAttributeMaxDynamicSharedMemorySize, LDSB);
  hipFuncSetAttribute((const void*)gemm2<0, false, true>,
                      hipFuncAttributeMaxDynamicSharedMemorySize, LDSB);
  hipFuncSetAttribute((const void*)gemm2<1, true, false>,
                      hipFuncAttributeMaxDynamicSharedMemorySize, LDSB);

  dim3 blk(256);
  dim3 gblk(512);
  cvt_f32_bf16<<<DD * DD / 4 / 256, blk, 0, stream>>>(Wq, Wqb, DD * DD / 4);
  cvt_f32_bf16<<<DD * DD / 4 / 256, blk, 0, stream>>>(Wk, Wkb, DD * DD / 4);
  cvt_f32_bf16<<<DD * DD / 4 / 256, blk, 0, stream>>>(Wv, Wvb, DD * DD / 4);
  cvt_f32_bf16<<<DD * DD / 4 / 256, blk, 0, stream>>>(Wo, Wob, DD * DD / 4);
  ln_rows<<<MM, blk, 0, stream>>>(x, ln1g, ln1b, hf, hb);
  // QKV projections (V written transposed per-head): grids (M/256)*(N/128)
  gemm2<1, false, false><<<256, gblk, LDSB, stream>>>(hb, Wqb, bq, nullptr, qbf, MM, DD, DD);
  gemm2<1, false, false><<<256, gblk, LDSB, stream>>>(hb, Wkb, bk, nullptr, kbf, MM, DD, DD);
  gemm2<2, false, false><<<256, gblk, LDSB, stream>>>(hb, Wvb, bv, nullptr, vTt, MM, DD, DD);
  attn_fwd<<<512, blk, 0, stream>>>(qbf, kbf, vTt, aob);
  gemm2<0, false, true><<<256, gblk, LDSB, stream>>>(aob, Wob, bo, hf, h2in, MM, DD, DD);
  ln_rows<<<MM, blk, 0, stream>>>(h2in, ln2g, ln2b, h2f, h2b);
  cvt_f32_bf16<<<D4 * DD / 4 / 256, blk, 0, stream>>>(W1, W1b, D4 * DD / 4);
  cvt_f32_bf16<<<D4 * DD / 4 / 256, blk, 0, stream>>>(W2, W2b, D4 * DD / 4);
  gemm2<1, true, false><<<1024, gblk, LDSB, stream>>>(h2b, W1b, b1, nullptr, gb, MM, D4, DD);
  gemm2<0, false, true><<<256, gblk, LDSB, stream>>>(gb, W2b, b2, h2f, out, MM, DD, D4);
}